// Round 6
// baseline (2115.908 us; speedup 1.0000x reference)
//
#include <hip/hip_runtime.h>

#define HID 512
#define TSTEPS 1000
#define NB 128
#define NIN 5
#define NOUT 2
#define ROWW 516                   // wT2 row: 512 w_rec cols + y0 + y1 + 2 pad
#define ROWB (ROWW * 4)            // 2064 bytes/row
#define DUMMYOFF (HID * ROWB)      // byte offset of the all-zeros row (j=512)
#define CHUNK 8                    // groups (of 4 entries) per pipeline stage

// Build wT2[j][h]: h<512 -> w_rec[h][j]; h=512/513 -> w_out[h-512][j]; else 0.
// Row j=512 is all zeros (padding target). Re-run every launch (ws re-poisoned).
__global__ void snn_prep(const float* __restrict__ w_rec,
                         const float* __restrict__ w_out,
                         float* __restrict__ wT2) {
  int idx = blockIdx.x * 256 + threadIdx.x;
  const int total = (HID + 1) * ROWW;
  if (idx >= total) return;
  int j = idx / ROWW;
  int h = idx - j * ROWW;
  float v = 0.0f;
  if (j < HID) {
    if (h < HID) v = w_rec[h * HID + j];
    else if (h < HID + NOUT) v = w_out[(h - HID) * HID + j];
  }
  wT2[idx] = v;
}

// 320 threads = 5 waves. tid<256: units 2t,2t+1. tid==256: readout (cols 512/513).
// One barrier/step; double-buffered per-wave spike segments; deep-pipelined
// (2 x CHUNK groups in flight) L2 column gather, ascending-j serial fp32 adds.
__global__ __launch_bounds__(320) void snn_main(
    const float* __restrict__ x,      // [T][B][5]
    const float* __restrict__ w_in,   // [H][5]
    const float* __restrict__ wT2,    // [513][516]
    float* __restrict__ out)          // [T][B][2]
{
#pragma clang fp contract(off)
  const int b = blockIdx.x;
  const int tid = threadIdx.x;
  const int lane = tid & 63;
  const int wv = tid >> 6;            // 0..4
  const int h0 = tid * 2;             // 512 for the readout lane

  __shared__ int __align__(16) s_seg[2][4][132];   // [buf][wave][padded entries]
  __shared__ int __align__(16) s_cnt[2][4];        // padded per-wave counts

  // per-unit input weights
  float wi00 = 0, wi01 = 0, wi02 = 0, wi03 = 0, wi04 = 0;
  float wi10 = 0, wi11 = 0, wi12 = 0, wi13 = 0, wi14 = 0;
  if (tid < 256) {
    const float* wa = w_in + h0 * NIN;
    wi00 = wa[0]; wi01 = wa[1]; wi02 = wa[2]; wi03 = wa[3]; wi04 = wa[4];
    const float* wb = w_in + (h0 + 1) * NIN;
    wi10 = wb[0]; wi11 = wb[1]; wi12 = wb[2]; wi13 = wb[3]; wi14 = wb[4];
  }

  // state
  float v0 = 0, v1 = 0, c0 = 0, c1 = 0;            // LIF pairs
  float io0 = 0, io1 = 0, vo0 = 0, vo1 = 0;        // LI readout (tid 256)
  float pend0 = 0, pend1 = 0;

  // x_0
  float xr0, xr1, xr2, xr3, xr4;
  {
    const float* xp = x + (size_t)b * NIN;
    xr0 = xp[0]; xr1 = xp[1]; xr2 = xp[2]; xr3 = xp[3]; xr4 = xp[4];
  }

  if (tid < 4) s_cnt[0][tid] = 0;
  __syncthreads();

  const char* wtb = (const char*)wT2 + (size_t)h0 * 4;

  for (int t = 0; t < TSTEPS; ++t) {
    const int rb = t & 1, wbuf = rb ^ 1;

    // deferred out store (drains during this step's gather)
    if (tid == 256 && t > 0) {
      float2 po; po.x = pend0; po.y = pend1;
      *(float2*)(out + (size_t)(t - 1) * NB * NOUT + b * NOUT) = po;
    }

    // prefetch x_{t+1}
    float nx0, nx1, nx2, nx3, nx4;
    {
      const int tn = (t + 1 < TSTEPS) ? t + 1 : t;
      const float* xp = x + ((size_t)tn * NB + b) * NIN;
      nx0 = xp[0]; nx1 = xp[1]; nx2 = xp[2]; nx3 = xp[3]; nx4 = xp[4];
    }

    // padded per-wave counts of z_{t-1} (single b128 read)
    const int4 c4 = *(const int4*)&s_cnt[rb][0];
    const int pc0 = __builtin_amdgcn_readfirstlane(c4.x);
    const int pc1 = __builtin_amdgcn_readfirstlane(c4.y);
    const int pc2 = __builtin_amdgcn_readfirstlane(c4.z);
    const int pc3 = __builtin_amdgcn_readfirstlane(c4.w);
    const int b1 = pc0, b2v = b1 + pc1, b3v = b2v + pc2;
    const int tot = b3v + pc3;
    const int ng = tot >> 2;   // groups of 4 entries

    float racc0 = 0.0f, racc1 = 0.0f;
    if (h0 < HID + NOUT && ng > 0) {
      const char* segbase = (const char*)&s_seg[rb][0][0];

#define SEGADDR(GI, AP) { int w_ = 0, bw_ = 0;                         \
      if ((GI) >= b1)  { w_ = 1; bw_ = b1;  }                          \
      if ((GI) >= b2v) { w_ = 2; bw_ = b2v; }                          \
      if ((GI) >= b3v) { w_ = 3; bw_ = b3v; }                          \
      AP = segbase + w_ * 528 + ((GI) - bw_) * 4; }

      // stage CHUNK groups starting at group CB into float2 array F (4*CHUNK)
#define STAGE_CHUNK(CB, F) {                                           \
      _Pragma("unroll")                                                \
      for (int q_ = 0; q_ < CHUNK; ++q_) {                             \
        const int gi4_ = ((CB) + q_) * 4;                              \
        const int gcl_ = (gi4_ < tot) ? gi4_ : 0;                      \
        const char* ap_; SEGADDR(gcl_, ap_);                           \
        int4 jv_ = *(const int4*)ap_;                                  \
        if (gi4_ >= tot) { jv_.x = DUMMYOFF; jv_.y = DUMMYOFF;         \
                           jv_.z = DUMMYOFF; jv_.w = DUMMYOFF; }       \
        F[4 * q_ + 0] = *(const float2*)(wtb + jv_.x);                 \
        F[4 * q_ + 1] = *(const float2*)(wtb + jv_.y);                 \
        F[4 * q_ + 2] = *(const float2*)(wtb + jv_.z);                 \
        F[4 * q_ + 3] = *(const float2*)(wtb + jv_.w);                 \
      } }

#define CONSUME_CHUNK(F) {                                             \
      _Pragma("unroll")                                                \
      for (int q_ = 0; q_ < 4 * CHUNK; ++q_) {                         \
        racc0 = __fadd_rn(racc0, F[q_].x);                             \
        racc1 = __fadd_rn(racc1, F[q_].y);                             \
      } }

      float2 FA[4 * CHUNK], FB[4 * CHUNK];
      STAGE_CHUNK(0, FA);
      int c = CHUNK;
      for (; c + CHUNK < ng; c += 2 * CHUNK) {
        STAGE_CHUNK(c, FB);
        CONSUME_CHUNK(FA);
        STAGE_CHUNK(c + CHUNK, FA);
        CONSUME_CHUNK(FB);
      }
      if (c < ng) {
        STAGE_CHUNK(c, FB);
        CONSUME_CHUNK(FA);
        CONSUME_CHUNK(FB);
      } else {
        CONSUME_CHUNK(FA);
      }
    }

    if (tid < 256) {
      // input currents (ascending-k chain)
      float a0 = __fmul_rn(xr0, wi00);
      a0 = fmaf(xr1, wi01, a0); a0 = fmaf(xr2, wi02, a0);
      a0 = fmaf(xr3, wi03, a0); a0 = fmaf(xr4, wi04, a0);
      float a1 = __fmul_rn(xr0, wi10);
      a1 = fmaf(xr1, wi11, a1); a1 = fmaf(xr2, wi12, a1);
      a1 = fmaf(xr3, wi13, a1); a1 = fmaf(xr4, wi14, a1);

      const float vd0 = __fadd_rn(v0, __fmul_rn(0.1f, __fsub_rn(c0, v0)));
      const float vd1 = __fadd_rn(v1, __fmul_rn(0.1f, __fsub_rn(c1, v1)));
      const bool s0 = vd0 > 1.0f;
      const bool s1 = vd1 > 1.0f;
      v0 = s0 ? 0.0f : vd0;
      v1 = s1 ? 0.0f : vd1;
      c0 = __fadd_rn(__fmul_rn(0.8f, c0), __fadd_rn(a0, racc0));
      c1 = __fadd_rn(__fmul_rn(0.8f, c1), __fadd_rn(a1, racc1));

      // publish spikes: per-wave segment, ascending j = 2*lane+parity
      const unsigned long long me = __ballot(s0);
      const unsigned long long mo = __ballot(s1);
      const unsigned long long below = (1ull << lane) - 1ull;
      const int cb = __popcll(me & below) + __popcll(mo & below);
      const int cnt = __popcll(me) + __popcll(mo);
      const int pcw = (cnt + 3) & ~3;
      int* seg = &s_seg[wbuf][wv][0];
      if (s0) seg[cb] = h0 * ROWB;
      if (s1) seg[cb + (s0 ? 1 : 0)] = (h0 + 1) * ROWB;
      if (lane < pcw - cnt) seg[cnt + lane] = DUMMYOFF;
      if (lane == 0) s_cnt[wbuf][wv] = pcw;
    } else if (tid == 256) {
      // racc = y_t; io_t = 0.8*io_{t-1} + y_t; vo uses OLD io -> out[t]
      io0 = __fadd_rn(__fmul_rn(0.8f, io0), racc0);
      io1 = __fadd_rn(__fmul_rn(0.8f, io1), racc1);
      vo0 = __fadd_rn(vo0, __fmul_rn(0.1f, __fsub_rn(io0, vo0)));
      vo1 = __fadd_rn(vo1, __fmul_rn(0.1f, __fsub_rn(io1, vo1)));
      pend0 = vo0; pend1 = vo1;
    }

    xr0 = nx0; xr1 = nx1; xr2 = nx2; xr3 = nx3; xr4 = nx4;
    __syncthreads();   // single barrier: step t's segment visible for t+1
  }

  if (tid == 256) {
    float2 po; po.x = pend0; po.y = pend1;
    *(float2*)(out + (size_t)(TSTEPS - 1) * NB * NOUT + b * NOUT) = po;
  }
}

extern "C" void kernel_launch(void* const* d_in, const int* in_sizes, int n_in,
                              void* d_out, int out_size, void* d_ws, size_t ws_size,
                              hipStream_t stream) {
  const float* x     = (const float*)d_in[0];
  const float* w_in  = (const float*)d_in[1];
  const float* w_rec = (const float*)d_in[2];
  const float* w_out = (const float*)d_in[3];
  float* out = (float*)d_out;
  float* wT2 = (float*)d_ws;   // (513*516)*4 ~= 1.06 MB

  const int prep_elems = (HID + 1) * ROWW;
  snn_prep<<<(prep_elems + 255) / 256, 256, 0, stream>>>(w_rec, w_out, wT2);
  snn_main<<<NB, 320, 0, stream>>>(x, w_in, wT2, out);
}